// Round 17
// baseline (243.402 us; speedup 1.0000x reference)
//
#include <hip/hip_runtime.h>
#include <hip/hip_fp16.h>
#include <stdint.h>

#define HH 8
#define CC 32
#define HC 256   // H*C
#define FF 128
#define NEG 0.2f
#define LNEPS 1e-5f
#define NR 8     // histogram replicas

typedef __attribute__((ext_vector_type(8))) short bf16x8;
typedef __attribute__((ext_vector_type(4))) float f32x4;
typedef unsigned short u16;

// ---------- helpers ----------
__device__ inline unsigned bf16r(float f) {           // round-to-nearest-even bf16
  unsigned u = __float_as_uint(f);
  return (u + 0x7fffu + ((u >> 16) & 1u)) >> 16;
}
__device__ inline float bflo(unsigned w) { return __uint_as_float(w << 16); }
__device__ inline float bfhi(unsigned w) { return __uint_as_float(w & 0xffff0000u); }
__device__ inline float leaky(float v) { return v >= 0.f ? v : NEG * v; }
__device__ inline float h2f(unsigned hbits) {
  return __half2float(__ushort_as_half((unsigned short)hbits));
}
__device__ inline u16 f2h(float f) {
  return __half_as_ushort(__float2half(f));
}
// byte extract -> float (v_cvt_f32_ubyte0..3)
__device__ inline float ub0(unsigned w) { return (float)(w & 0xffu); }
__device__ inline float ub1(unsigned w) { return (float)((w >> 8) & 0xffu); }
__device__ inline float ub2(unsigned w) { return (float)((w >> 16) & 0xffu); }
__device__ inline float ub3(unsigned w) { return (float)(w >> 24); }

// ---------- KLAYOUT: repack weights into MFMA B-fragment layout (bf16) ----------
__global__ __launch_bounds__(256) void klayout(
    const float* __restrict__ W, const float* __restrict__ atts,
    const float* __restrict__ attd, const float* __restrict__ w1,
    const float* __restrict__ w2,
    u16* __restrict__ Wb, u16* __restrict__ Zb,
    u16* __restrict__ V1b, u16* __restrict__ V2b, u16* __restrict__ WSb)
{
  int t0 = (int)blockIdx.x * 256 + (int)threadIdx.x;
  int st = (int)gridDim.x * 256;
  for (int i = t0; i < 16 * 512; i += st) {        // Wb: W_gat [32,256]
    int j = i & 7, l = (i >> 3) & 63, nb = i >> 9;
    int k = 8 * (l >> 4) + j, c = 16 * nb + (l & 15);
    Wb[i] = (u16)bf16r(W[k * HC + c]);
  }
  for (int i = t0; i < 8 * 512; i += st) {         // Zb: [256,16] = [atts|attd] blockdiag
    int j = i & 7, l = (i >> 3) & 63, kb = i >> 9;
    int k = 32 * kb + 8 * (l >> 4) + j;
    int tc = l & 15;
    float v = 0.f;
    if (tc < 8)  { if ((k >> 5) == tc)     v = atts[tc * 32 + (k & 31)]; }
    else         { if ((k >> 5) == tc - 8) v = attd[(tc - 8) * 32 + (k & 31)]; }
    Zb[i] = (u16)bf16r(v);
  }
  for (int i = t0; i < 8 * 512; i += st) {         // V1b: w1 [32,128]
    int j = i & 7, l = (i >> 3) & 63, nb = i >> 9;
    int k = 8 * (l >> 4) + j, c = 16 * nb + (l & 15);
    V1b[i] = (u16)bf16r(w1[k * FF + c]);
  }
  for (int i = t0; i < 8 * 512; i += st) {         // V2b: w2 [128,32]
    int j = i & 7, l = (i >> 3) & 63, kn = i >> 9;
    int kb = kn >> 1, nb2 = kn & 1;
    int k = 32 * kb + 8 * (l >> 4) + j, c = 16 * nb2 + (l & 15);
    V2b[i] = (u16)bf16r(w2[k * CC + c]);
  }
  for (int i = t0; i < 16 * 512; i += st) {        // WSb: Wstack [256,32]
    int j = i & 7, l = (i >> 3) & 63, kn = i >> 9; // Wstack[h*32+k][c]=W[k][h*32+c]
    int kb = kn >> 1, nb2 = kn & 1;
    int krow = kb * 32 + 8 * (l >> 4) + j;         // 0..255
    int h = krow >> 5, kk = krow & 31;
    int c = 16 * nb2 + (l & 15);
    WSb[i] = (u16)bf16r(W[kk * HC + h * 32 + c]);
  }
}

// ---------- K1C (fused): MFMA a-dots + int8 x -> combo  ||  8-replica histogram ----------
// combo row per node (16 dwords = 64B): [0..7] = (bf16 a_src | fp16 xscale) per head,
//                                       [8..15] = int8 x (32 bytes)
__global__ __launch_bounds__(256) void k1c(
    const float* __restrict__ x, const u16* __restrict__ Wb,
    const u16* __restrict__ Zb, const int* __restrict__ ei,
    unsigned* __restrict__ combo, float* __restrict__ a_d,
    int* __restrict__ deg8, unsigned* __restrict__ dstr, int n, int e, int nbc)
{
  if ((int)blockIdx.x >= nbc) {                    // histogram + rank role
    int bi = (int)blockIdx.x - nbc;
    int r = bi & (NR - 1);
    int* dr = deg8 + (size_t)r * n;
    int i = bi * 1024 + (int)threadIdx.x * 4;
    if (i >= e) return;
    const int* dst = ei + e;
    if (i + 3 < e) {
      int4 d4 = *(const int4*)(dst + i);
      unsigned r0 = (unsigned)atomicAdd(&dr[d4.x], 1);
      unsigned r1 = (unsigned)atomicAdd(&dr[d4.y], 1);
      unsigned r2 = (unsigned)atomicAdd(&dr[d4.z], 1);
      unsigned r3 = (unsigned)atomicAdd(&dr[d4.w], 1);
      uint4 o;
      o.x = (unsigned)d4.x | ((unsigned)r << 17) | (r0 << 20);
      o.y = (unsigned)d4.y | ((unsigned)r << 17) | (r1 << 20);
      o.z = (unsigned)d4.z | ((unsigned)r << 17) | (r2 << 20);
      o.w = (unsigned)d4.w | ((unsigned)r << 17) | (r3 << 20);
      *(uint4*)(dstr + i) = o;
    } else {
      for (int k = 0; k < 4 && i + k < e; ++k) {
        int d = dst[i + k];
        unsigned rr = (unsigned)atomicAdd(&dr[d], 1);
        dstr[i + k] = (unsigned)d | ((unsigned)r << 17) | (rr << 20);
      }
    }
    return;
  }
  __shared__ u16 lt[4][16 * 264];                  // per-wave [16 rows][264 halfs]
  int wid = threadIdx.x >> 6, lane = threadIdx.x & 63;
  int q = lane & 15, g = lane >> 4;
  long node0 = (long)((int)blockIdx.x * 4 + wid) * 16;
  if (node0 + 16 > n) node0 = n - 16;              // overlap tail: duplicate identical writes
  u16* L = lt[wid];
  u16* combo16 = (u16*)combo;

  // A-frag: x[node0+q][8g..8g+7] -> bf16; keep fp32 copies for quantization
  const float* xr = x + (node0 + q) * CC + 8 * g;
  float4 xa = *(const float4*)xr, xb = *(const float4*)(xr + 4);
  bf16x8 af;
  af[0] = (short)bf16r(xa.x); af[1] = (short)bf16r(xa.y);
  af[2] = (short)bf16r(xa.z); af[3] = (short)bf16r(xa.w);
  af[4] = (short)bf16r(xb.x); af[5] = (short)bf16r(xb.y);
  af[6] = (short)bf16r(xb.z); af[7] = (short)bf16r(xb.w);

  // ---- per-node x absmax over 32 ch (4 lanes share q: xor 16, 32) ----
  float mx = fmaxf(fmaxf(fmaxf(fabsf(xa.x), fabsf(xa.y)), fmaxf(fabsf(xa.z), fabsf(xa.w))),
                   fmaxf(fmaxf(fabsf(xb.x), fabsf(xb.y)), fmaxf(fabsf(xb.z), fabsf(xb.w))));
  mx = fmaxf(mx, __shfl_xor(mx, 16));
  mx = fmaxf(mx, __shfl_xor(mx, 32));
  float rinv = (mx > 0.f) ? 127.f / mx : 0.f;
  u16 sch = f2h(mx * (1.f / 127.f));
  combo16[((node0 + q) * 16 + 2 * g) * 2 + 1]     = sch;
  combo16[((node0 + q) * 16 + 2 * g + 1) * 2 + 1] = sch;
  {
    int q0 = min(max(__float2int_rn(xa.x * rinv), -127), 127) + 128;
    int q1 = min(max(__float2int_rn(xa.y * rinv), -127), 127) + 128;
    int q2 = min(max(__float2int_rn(xa.z * rinv), -127), 127) + 128;
    int q3 = min(max(__float2int_rn(xa.w * rinv), -127), 127) + 128;
    int q4 = min(max(__float2int_rn(xb.x * rinv), -127), 127) + 128;
    int q5 = min(max(__float2int_rn(xb.y * rinv), -127), 127) + 128;
    int q6 = min(max(__float2int_rn(xb.z * rinv), -127), 127) + 128;
    int q7 = min(max(__float2int_rn(xb.w * rinv), -127), 127) + 128;
    uint2 pk;
    pk.x = (unsigned)q0 | ((unsigned)q1 << 8) | ((unsigned)q2 << 16) | ((unsigned)q3 << 24);
    pk.y = (unsigned)q4 | ((unsigned)q5 << 8) | ((unsigned)q6 << 16) | ((unsigned)q7 << 24);
    *(uint2*)(combo + (node0 + q) * 16 + 8 + 2 * g) = pk;
  }

  // ---- xp = x@W into LDS (needed only for the a-dots) ----
#pragma unroll
  for (int nb = 0; nb < 16; ++nb) {
    bf16x8 bf = *(const bf16x8*)(Wb + nb * 512 + lane * 8);
    f32x4 acc = {0.f, 0.f, 0.f, 0.f};
    acc = __builtin_amdgcn_mfma_f32_16x16x32_bf16(af, bf, acc, 0, 0, 0);
    int col = 16 * nb + q;
#pragma unroll
    for (int r = 0; r < 4; ++r)
      L[(4 * g + r) * 264 + col] = (u16)bf16r(acc[r]);
  }
  __syncthreads();

  // a_src/a_dst: [16 nodes,256] x [256,16] via 8 chained mfma
  f32x4 az = {0.f, 0.f, 0.f, 0.f};
#pragma unroll
  for (int kb = 0; kb < 8; ++kb) {
    bf16x8 a2 = *(const bf16x8*)(L + q * 264 + kb * 32 + g * 8);
    bf16x8 zb = *(const bf16x8*)(Zb + kb * 512 + lane * 8);
    az = __builtin_amdgcn_mfma_f32_16x16x32_bf16(a2, zb, az, 0, 0, 0);
  }
  int hq = q & 7;
  if (q < 8) {                                     // a_src -> combo lo16 (bf16)
#pragma unroll
    for (int r = 0; r < 4; ++r)
      combo16[((node0 + 4 * g + r) * 16 + hq) * 2] = (u16)bf16r(az[r]);
  } else {                                         // a_dst (fp32)
#pragma unroll
    for (int r = 0; r < 4; ++r)
      a_d[(node0 + 4 * g + r) * HH + hq] = az[r];
  }
}

// ---------- scan phase A: per-1024-block sums (over NR replicas) ----------
__global__ __launch_bounds__(256) void kscanA(const int* __restrict__ deg8,
                                              int* __restrict__ bsum, int n)
{
  __shared__ int ws[4];
  int t = threadIdx.x;
  int i = (int)blockIdx.x * 1024 + t * 4;
  int s = 0;
  if (i + 3 < n) {
#pragma unroll
    for (int r = 0; r < NR; ++r) {
      int4 v = *(const int4*)(deg8 + (size_t)r * n + i);
      s += v.x + v.y + v.z + v.w;
    }
  } else {
    for (int k = 0; k < 4 && i + k < n; ++k)
#pragma unroll
      for (int r = 0; r < NR; ++r) s += deg8[(size_t)r * n + i + k];
  }
#pragma unroll
  for (int mask = 1; mask < 64; mask <<= 1) s += __shfl_xor(s, mask);
  if ((t & 63) == 0) ws[t >> 6] = s;
  __syncthreads();
  if (t == 0) bsum[blockIdx.x] = ws[0] + ws[1] + ws[2] + ws[3];
}

// ---------- scan phase B ----------
__global__ __launch_bounds__(1024) void kscanB(int* __restrict__ bsum, int nb)
{
  __shared__ int wsum[16];
  int t = threadIdx.x, lane = t & 63, wid = t >> 6;
  int v = (t < nb) ? bsum[t] : 0;
  int s = v;
#pragma unroll
  for (int d = 1; d < 64; d <<= 1) { int tt = __shfl_up(s, d); if (lane >= d) s += tt; }
  if (lane == 63) wsum[wid] = s;
  __syncthreads();
  if (wid == 0) {
    int w = (lane < 16) ? wsum[lane] : 0;
#pragma unroll
    for (int d = 1; d < 16; d <<= 1) { int tt = __shfl_up(w, d); if (lane >= d) w += tt; }
    if (lane < 16) wsum[lane] = w;
  }
  __syncthreads();
  int excl = s - v + ((wid > 0) ? wsum[wid - 1] : 0);
  if (t < nb) bsum[t] = excl;
}

// ---------- scan phase C: per-replica bases rb[0..NR-1] + degt ----------
__global__ __launch_bounds__(256) void kscanC(const int* __restrict__ deg8,
                                              const int* __restrict__ bsum,
                                              int* __restrict__ rb,
                                              int* __restrict__ degt, int n)
{
  __shared__ int ws[4];
  int t = threadIdx.x, lane = t & 63, wid = t >> 6;
  int i = (int)blockIdx.x * 1024 + t * 4;
  int cr[NR][4];
#pragma unroll
  for (int r = 0; r < NR; ++r) {
    if (i + 3 < n) {
      int4 v = *(const int4*)(deg8 + (size_t)r * n + i);
      cr[r][0] = v.x; cr[r][1] = v.y; cr[r][2] = v.z; cr[r][3] = v.w;
    } else {
      for (int k = 0; k < 4; ++k)
        cr[r][k] = (i + k < n) ? deg8[(size_t)r * n + i + k] : 0;
    }
  }
  int tot[4];
#pragma unroll
  for (int k = 0; k < 4; ++k) {
    int s = 0;
#pragma unroll
    for (int r = 0; r < NR; ++r) s += cr[r][k];
    tot[k] = s;
  }
  int tsum = tot[0] + tot[1] + tot[2] + tot[3];
  int s = tsum;
#pragma unroll
  for (int d = 1; d < 64; d <<= 1) { int tt = __shfl_up(s, d); if (lane >= d) s += tt; }
  if (lane == 63) ws[wid] = s;
  __syncthreads();
  if (t == 0) {
    int a = ws[0]; ws[0] = 0;
    int b = ws[1]; ws[1] = a; a += b;
    int c = ws[2]; ws[2] = a; a += c;
    ws[3] = a;
  }
  __syncthreads();
  int base = bsum[blockIdx.x] + ws[wid] + (s - tsum);
#pragma unroll
  for (int k = 0; k < 4; ++k) {
    if (i + k < n) {
      int b0 = base;
#pragma unroll
      for (int r = 0; r < NR; ++r) {
        rb[(size_t)r * n + i + k] = b0;
        b0 += cr[r][k];
      }
      degt[i + k] = tot[k];
    }
    base += tot[k];
  }
}

// ---------- CSR scatter: rank-based, ATOMIC-FREE, dst-quadrant L2-local writes ----------
__global__ __launch_bounds__(256) void kscatter(
    const int* __restrict__ ei, const unsigned* __restrict__ dstr, int e,
    const int* __restrict__ rb, int* __restrict__ csr, int n)
{
  int oct = (int)blockIdx.x & 3;
  int nsub = (int)gridDim.x >> 2;
  int sub = (int)blockIdx.x >> 2;
  int nper = (n + 3) >> 2;
  int lo = oct * nper, hi = lo + nper;
  int stride = nsub << 10;
  for (int i = (sub * 256 + (int)threadIdx.x) * 4; i < e; i += stride) {
    if (i + 3 < e) {
      uint4 d4 = *(const uint4*)(dstr + i);
      int4 s4 = *(const int4*)(ei + i);
      int dx = d4.x & 0x1ffff, dy = d4.y & 0x1ffff,
          dz = d4.z & 0x1ffff, dw = d4.w & 0x1ffff;
      if (dx >= lo && dx < hi)
        csr[rb[(size_t)((d4.x >> 17) & 7) * n + dx] + (d4.x >> 20)] = s4.x;
      if (dy >= lo && dy < hi)
        csr[rb[(size_t)((d4.y >> 17) & 7) * n + dy] + (d4.y >> 20)] = s4.y;
      if (dz >= lo && dz < hi)
        csr[rb[(size_t)((d4.z >> 17) & 7) * n + dz] + (d4.z >> 20)] = s4.z;
      if (dw >= lo && dw < hi)
        csr[rb[(size_t)((d4.w >> 17) & 7) * n + dw] + (d4.w >> 20)] = s4.w;
    } else {
      for (int k = 0; k < 4 && i + k < e; ++k) {
        unsigned dv = dstr[i + k];
        int d = dv & 0x1ffff;
        if (d >= lo && d < hi)
          csr[rb[(size_t)((dv >> 17) & 7) * n + d] + (dv >> 20)] = ei[i + k];
      }
    }
  }
}

// ---------- KAGG: raw-x aggregation, EDGE-PAIR B-phase (half the shfl/load issue) ----------
// A-layout: eg=lane>>3 (edge slot), ha=lane&7 (head) — compute (srcl, pw) per edge.
// B-layout: ep=lane>>5 (edge parity), hB=(lane>>2)&7 (head), c2=lane&3 (uint2 slot).
// Each lane accumulates 8 channels for its parity; merge via shfl_xor(·,32) per node.
__global__ __launch_bounds__(256) void kagg(
    const int* __restrict__ csr, const int* __restrict__ offs,
    const int* __restrict__ degt,
    const unsigned* __restrict__ combo, const float* __restrict__ a_d,
    unsigned* __restrict__ agg32, int n)
{
  int lane = threadIdx.x & 63;
  int wid  = threadIdx.x >> 6;
  int base = ((int)blockIdx.x * 4 + wid) * 4;      // 4 nodes per wave
  int eg = lane >> 3, ha = lane & 7;
  int ep = lane >> 5, hB = (lane >> 2) & 7, c2 = lane & 3;
  (void)ep;

  for (int t = 0; t < 4; ++t) {
    int node = base + t;
    if (node >= n) return;
    int start = offs[node];
    int dg = degt[node];
    unsigned aw_self = combo[(size_t)node * 16 + ha];
    float ad_a  = a_d[(size_t)node * HH + ha];
    float aself = leaky(bflo(aw_self) + ad_a);

    float acc[8] = {0.f, 0.f, 0.f, 0.f, 0.f, 0.f, 0.f, 0.f};
    float dnA = 0.f, osA = 0.f;

    for (int j0 = 0; j0 < dg; j0 += 8) {
      int cnt = dg - j0; if (cnt > 8) cnt = 8;
      int idx = j0 + eg;
      int srcl = 0; float pw = 0.f;
      if (idx < dg) {
        srcl = csr[start + idx];
        unsigned av = combo[(size_t)srcl * 16 + ha];   // first half of 64B line
        float al = leaky(bflo(av) + ad_a);
        float p  = __expf(al - aself);
        pw = p * h2f(av >> 16);                        // p * xscale_src
        dnA += p; osA += pw;
      }
      // pair loop: lane handles edge (j + ep); invalid slots have pw=0
      for (int j = 0; j < cnt; j += 2) {
        int sl = ((j + (lane >> 5)) << 3) + hB;
        float wt = __shfl(pw, sl);
        int s = __shfl(srcl, sl);
        uint2 w = *(const uint2*)(combo + (size_t)s * 16 + 8 + c2 * 2);
        acc[0] = fmaf(ub0(w.x), wt, acc[0]);
        acc[1] = fmaf(ub1(w.x), wt, acc[1]);
        acc[2] = fmaf(ub2(w.x), wt, acc[2]);
        acc[3] = fmaf(ub3(w.x), wt, acc[3]);
        acc[4] = fmaf(ub0(w.y), wt, acc[4]);
        acc[5] = fmaf(ub1(w.y), wt, acc[5]);
        acc[6] = fmaf(ub2(w.y), wt, acc[6]);
        acc[7] = fmaf(ub3(w.y), wt, acc[7]);
      }
    }

    // merge edge parities: both halves end holding the total
#pragma unroll
    for (int k = 0; k < 8; ++k) acc[k] += __shfl_xor(acc[k], 32);

    // reduce dn/osum over edge-slot dim (eg): per-head values at lane ha
    float dnH = dnA, osH = osA;
    dnH += __shfl_xor(dnH, 8);  osH += __shfl_xor(osH, 8);
    dnH += __shfl_xor(dnH, 16); osH += __shfl_xor(osH, 16);
    dnH += __shfl_xor(dnH, 32); osH += __shfl_xor(osH, 32);
    float dnB = __shfl(dnH, hB);
    float osB = __shfl(osH, hB);
    float scB = __shfl(h2f(aw_self >> 16), hB);    // xscale_node (head-replicated)

    // self loop: p = 1 (post-merge, every lane adds exactly once)
    {
      uint2 w = *(const uint2*)(combo + (size_t)node * 16 + 8 + c2 * 2);
      dnB += 1.f; osB += scB;
      acc[0] = fmaf(ub0(w.x), scB, acc[0]);
      acc[1] = fmaf(ub1(w.x), scB, acc[1]);
      acc[2] = fmaf(ub2(w.x), scB, acc[2]);
      acc[3] = fmaf(ub3(w.x), scB, acc[3]);
      acc[4] = fmaf(ub0(w.y), scB, acc[4]);
      acc[5] = fmaf(ub1(w.y), scB, acc[5]);
      acc[6] = fmaf(ub2(w.y), scB, acc[6]);
      acc[7] = fmaf(ub3(w.y), scB, acc[7]);
    }

    float corr = -128.f * osB;
    float inv = 0.125f / dnB;                      // fold 1/8 head-mean here
#pragma unroll
    for (int k = 0; k < 8; ++k) acc[k] = (acc[k] + corr) * inv;
    if (lane < 32) {
      uint4 pk;
      pk.x = bf16r(acc[0]) | (bf16r(acc[1]) << 16);
      pk.y = bf16r(acc[2]) | (bf16r(acc[3]) << 16);
      pk.z = bf16r(acc[4]) | (bf16r(acc[5]) << 16);
      pk.w = bf16r(acc[6]) | (bf16r(acc[7]) << 16);
      *(uint4*)(agg32 + (size_t)node * 128 + hB * 16 + c2 * 4) = pk;
    }
  }
}

// ---------- K5M: MFMA tail — og = agg@Wstack, + x + bg, LN1 + FFN(mfma) + LN2 ----------
__global__ __launch_bounds__(256) void k5m(
    const u16* __restrict__ agg16, const float* __restrict__ x,
    const float* __restrict__ bg, const u16* __restrict__ WSb,
    const u16* __restrict__ V1b, const u16* __restrict__ V2b,
    const float* __restrict__ b1, const float* __restrict__ b2,
    const float* __restrict__ g1, const float* __restrict__ be1,
    const float* __restrict__ g2, const float* __restrict__ be2,
    float* __restrict__ out, int n)
{
  __shared__ u16   lh[4][16 * 40];
  __shared__ u16   lf[4][16 * 136];
  __shared__ float lo[4][16 * 36];
  int wid = threadIdx.x >> 6, lane = threadIdx.x & 63;
  int q = lane & 15, g = lane >> 4;
  long node0 = (long)((int)blockIdx.x * 4 + wid) * 16;
  if (node0 + 16 > n) node0 = n - 16;
  u16* LH = lh[wid]; u16* LF = lf[wid]; float* LO = lo[wid];

  // stage x + bg cooperatively
  {
    int row = lane >> 2, off = (lane & 3) * 8;
    const float* x8 = x + (node0 + row) * CC + off;
    float4 c0 = *(const float4*)x8, c1 = *(const float4*)(x8 + 4);
    float4 bg0 = *(const float4*)(bg + off), bg1 = *(const float4*)(bg + off + 4);
    float4 s0 = make_float4(c0.x + bg0.x, c0.y + bg0.y, c0.z + bg0.z, c0.w + bg0.w);
    float4 s1 = make_float4(c1.x + bg1.x, c1.y + bg1.y, c1.z + bg1.z, c1.w + bg1.w);
    *(float4*)(LO + row * 36 + off)     = s0;
    *(float4*)(LO + row * 36 + off + 4) = s1;
  }
  __syncthreads();

  // og = agg @ Wstack  ([16,256] x [256,32]) then LO += og
  {
    f32x4 a20 = {0.f, 0.f, 0.f, 0.f}, a21 = {0.f, 0.f, 0.f, 0.f};
#pragma unroll
    for (int kb = 0; kb < 8; ++kb) {
      bf16x8 af = *(const bf16x8*)(agg16 + (node0 + q) * 256 + kb * 32 + g * 8);
      bf16x8 w0 = *(const bf16x8*)(WSb + (kb * 2 + 0) * 512 + lane * 8);
      bf16x8 w1v = *(const bf16x8*)(WSb + (kb * 2 + 1) * 512 + lane * 8);
      a20 = __builtin_amdgcn_mfma_f32_16x16x32_bf16(af, w0, a20, 0, 0, 0);
      a21 = __builtin_amdgcn_mfma_f32_16x16x32_bf16(af, w1v, a21, 0, 0, 0);
    }
#pragma unroll
    for (int r = 0; r < 4; ++r) {
      LO[(4 * g + r) * 36 + q]      += a20[r];
      LO[(4 * g + r) * 36 + 16 + q] += a21[r];
    }
  }
  __syncthreads();

  float hv[32];
  if (lane < 16) {
#pragma unroll
    for (int i = 0; i < 8; ++i) {
      float4 t = *(const float4*)(LO + q * 36 + i * 4);
      hv[4*i] = t.x; hv[4*i+1] = t.y; hv[4*i+2] = t.z; hv[4*i+3] = t.w;
    }
    float mu = 0.f;
#pragma unroll
    for (int c = 0; c < 32; ++c) mu += hv[c];
    mu *= (1.f / 32.f);
    float var = 0.f;
#pragma unroll
    for (int c = 0; c < 32; ++c) { float t = hv[c] - mu; var = fmaf(t, t, var); }
    float rs = rsqrtf(var * (1.f / 32.f) + LNEPS);
#pragma unroll
    for (int c = 0; c < 32; ++c) hv[c] = (hv[c] - mu) * rs * g1[c] + be1[c];
    uint* dst = (uint*)(LH + q * 40);
#pragma unroll
    for (int i = 0; i < 16; ++i)
      dst[i] = bf16r(hv[2*i]) | (bf16r(hv[2*i+1]) << 16);
  }
  __syncthreads();

  bf16x8 ah = *(const bf16x8*)(LH + q * 40 + g * 8);
#pragma unroll
  for (int nb = 0; nb < 8; ++nb) {
    bf16x8 v1 = *(const bf16x8*)(V1b + nb * 512 + lane * 8);
    f32x4 acc = {0.f, 0.f, 0.f, 0.f};
    acc = __builtin_amdgcn_mfma_f32_16x16x32_bf16(ah, v1, acc, 0, 0, 0);
    int col = 16 * nb + q;
    float bias = b1[col];
#pragma unroll
    for (int r = 0; r < 4; ++r) {
      float f = fmaxf(acc[r] + bias, 0.f);
      LF[(4 * g + r) * 136 + col] = (u16)bf16r(f);
    }
  }
  __syncthreads();

  f32x4 a20 = {0.f, 0.f, 0.f, 0.f}, a21 = {0.f, 0.f, 0.f, 0.f};
#pragma unroll
  for (int kb = 0; kb < 4; ++kb) {
    bf16x8 af2 = *(const bf16x8*)(LF + q * 136 + kb * 32 + g * 8);
    bf16x8 v20 = *(const bf16x8*)(V2b + (kb * 2 + 0) * 512 + lane * 8);
    bf16x8 v21 = *(const bf16x8*)(V2b + (kb * 2 + 1) * 512 + lane * 8);
    a20 = __builtin_amdgcn_mfma_f32_16x16x32_bf16(af2, v20, a20, 0, 0, 0);
    a21 = __builtin_amdgcn_mfma_f32_16x16x32_bf16(af2, v21, a21, 0, 0, 0);
  }
  __syncthreads();
#pragma unroll
  for (int r = 0; r < 4; ++r) {
    LO[(4 * g + r) * 36 + q]      = a20[r];
    LO[(4 * g + r) * 36 + 16 + q] = a21[r];
  }
  __syncthreads();

  if (lane < 16) {
    float ov[32];
#pragma unroll
    for (int i = 0; i < 8; ++i) {
      float4 t = *(const float4*)(LO + q * 36 + i * 4);
      ov[4*i] = t.x; ov[4*i+1] = t.y; ov[4*i+2] = t.z; ov[4*i+3] = t.w;
    }
#pragma unroll
    for (int c = 0; c < 32; ++c) ov[c] += b2[c] + hv[c];
    float mu2 = 0.f;
#pragma unroll
    for (int c = 0; c < 32; ++c) mu2 += ov[c];
    mu2 *= (1.f / 32.f);
    float var2 = 0.f;
#pragma unroll
    for (int c = 0; c < 32; ++c) { float t = ov[c] - mu2; var2 = fmaf(t, t, var2); }
    float rs2 = rsqrtf(var2 * (1.f / 32.f) + LNEPS);
    float* op = out + (node0 + q) * CC;
#pragma unroll
    for (int i = 0; i < 8; ++i) {
      float4 o;
      o.x = (ov[4*i]   - mu2) * rs2 * g2[4*i]   + be2[4*i];
      o.y = (ov[4*i+1] - mu2) * rs2 * g2[4*i+1] + be2[4*i+1];
      o.z = (ov[4*i+2] - mu2) * rs2 * g2[4*i+2] + be2[4*i+2];
      o.w = (ov[4*i+3] - mu2) * rs2 * g2[4*i+3] + be2[4*i+3];
      *(float4*)(op + i * 4) = o;
    }
  }
}

// ---------- launch ----------
extern "C" void kernel_launch(void* const* d_in, const int* in_sizes, int n_in,
                              void* d_out, int out_size, void* d_ws, size_t ws_size,
                              hipStream_t stream)
{
  const float* x    = (const float*)d_in[0];
  const int*   ei   = (const int*)d_in[1];
  const float* W    = (const float*)d_in[2];
  const float* atts = (const float*)d_in[3];
  const float* attd = (const float*)d_in[4];
  const float* bg   = (const float*)d_in[5];
  const float* w1   = (const float*)d_in[6];
  const float* b1   = (const float*)d_in[7];
  const float* w2   = (const float*)d_in[8];
  const float* b2   = (const float*)d_in[9];
  const float* g1   = (const float*)d_in[10];
  const float* be1  = (const float*)d_in[11];
  const float* g2   = (const float*)d_in[12];
  const float* be2  = (const float*)d_in[13];

  int n = in_sizes[0] / CC;
  int e = in_sizes[1] / 2;

  uint8_t* ws = (uint8_t*)d_ws;
  size_t o = 0;
  unsigned* combo = (unsigned*)(ws + o); o += (size_t)n * 64;    // 64B/node: ascp+xqx
  float* a_d = (float*)(ws + o); o += (size_t)n * HH * 4;
  unsigned* agg32 = (unsigned*)(ws + o); o += (size_t)n * 512;   // bf16 agg [N,256]
  int* deg8   = (int*)(ws + o); o += (size_t)n * NR * 4;
  int* rb     = (int*)(ws + o); o += (size_t)n * NR * 4;
  int* degt   = (int*)(ws + o); o += (size_t)n * 4;
  unsigned* dstr = (unsigned*)(ws + o); o += (size_t)e * 4;
  int* csr    = (int*)(ws + o); o += (size_t)e * 4;
  int* bsum   = (int*)(ws + o); o += 4096;
  u16* Wb  = (u16*)(ws + o); o += 16 * 512 * 2;
  u16* Zb  = (u16*)(ws + o); o += 8 * 512 * 2;
  u16* V1b = (u16*)(ws + o); o += 8 * 512 * 2;
  u16* V2b = (u16*)(ws + o); o += 8 * 512 * 2;
  u16* WSb = (u16*)(ws + o); o += 16 * 512 * 2;

  (void)hipMemsetAsync(deg8, 0, (size_t)n * NR * 4, stream);

  int nwaves = (n + 15) / 16;
  int nbc   = (nwaves + 3) / 4;
  int nb_e4 = (e + 1023) / 1024;
  int nb_s  = (n + 1023) / 1024;
  int nb_ag = (n + 15) / 16;        // 4 waves x 4 nodes = 16 nodes per block

  klayout <<<16, 256, 0, stream>>>(W, atts, attd, w1, w2, Wb, Zb, V1b, V2b, WSb);
  k1c     <<<nbc + nb_e4, 256, 0, stream>>>(x, Wb, Zb, ei, combo, a_d, deg8,
                                            dstr, n, e, nbc);
  kscanA  <<<nb_s, 256, 0, stream>>>(deg8, bsum, n);
  kscanB  <<<1, 1024, 0, stream>>>(bsum, nb_s);
  kscanC  <<<nb_s, 256, 0, stream>>>(deg8, bsum, rb, degt, n);
  kscatter<<<512, 256, 0, stream>>>(ei, dstr, e, rb, csr, n);
  kagg    <<<nb_ag, 256, 0, stream>>>(csr, rb, degt, combo, a_d, agg32, n);
  k5m     <<<nbc, 256, 0, stream>>>((const u16*)agg32, x, bg, WSb, V1b, V2b,
                                    b1, b2, g1, be1, g2, be2, (float*)d_out, n);
}

// Round 18
// 218.844 us; speedup vs baseline: 1.1122x; 1.1122x over previous
//
#include <hip/hip_runtime.h>
#include <hip/hip_fp16.h>
#include <stdint.h>

#define HH 8
#define CC 32
#define HC 256   // H*C
#define FF 128
#define NEG 0.2f
#define LNEPS 1e-5f
#define NR 8     // histogram replicas

typedef __attribute__((ext_vector_type(8))) short bf16x8;
typedef __attribute__((ext_vector_type(4))) float f32x4;
typedef unsigned short u16;

// ---------- helpers ----------
__device__ inline unsigned bf16r(float f) {           // round-to-nearest-even bf16
  unsigned u = __float_as_uint(f);
  return (u + 0x7fffu + ((u >> 16) & 1u)) >> 16;
}
__device__ inline float bflo(unsigned w) { return __uint_as_float(w << 16); }
__device__ inline float bfhi(unsigned w) { return __uint_as_float(w & 0xffff0000u); }
__device__ inline float leaky(float v) { return v >= 0.f ? v : NEG * v; }
__device__ inline float h2f(unsigned hbits) {
  return __half2float(__ushort_as_half((unsigned short)hbits));
}
__device__ inline u16 f2h(float f) {
  return __half_as_ushort(__float2half(f));
}
// byte extract -> float (v_cvt_f32_ubyte0..3)
__device__ inline float ub0(unsigned w) { return (float)(w & 0xffu); }
__device__ inline float ub1(unsigned w) { return (float)((w >> 8) & 0xffu); }
__device__ inline float ub2(unsigned w) { return (float)((w >> 16) & 0xffu); }
__device__ inline float ub3(unsigned w) { return (float)(w >> 24); }

// ---------- KLAYOUT: repack weights into MFMA B-fragment layout (bf16) ----------
__global__ __launch_bounds__(256) void klayout(
    const float* __restrict__ W, const float* __restrict__ atts,
    const float* __restrict__ attd, const float* __restrict__ w1,
    const float* __restrict__ w2,
    u16* __restrict__ Wb, u16* __restrict__ Zb,
    u16* __restrict__ V1b, u16* __restrict__ V2b, u16* __restrict__ WSb)
{
  int t0 = (int)blockIdx.x * 256 + (int)threadIdx.x;
  int st = (int)gridDim.x * 256;
  for (int i = t0; i < 16 * 512; i += st) {        // Wb: W_gat [32,256]
    int j = i & 7, l = (i >> 3) & 63, nb = i >> 9;
    int k = 8 * (l >> 4) + j, c = 16 * nb + (l & 15);
    Wb[i] = (u16)bf16r(W[k * HC + c]);
  }
  for (int i = t0; i < 8 * 512; i += st) {         // Zb: [256,16] = [atts|attd] blockdiag
    int j = i & 7, l = (i >> 3) & 63, kb = i >> 9;
    int k = 32 * kb + 8 * (l >> 4) + j;
    int tc = l & 15;
    float v = 0.f;
    if (tc < 8)  { if ((k >> 5) == tc)     v = atts[tc * 32 + (k & 31)]; }
    else         { if ((k >> 5) == tc - 8) v = attd[(tc - 8) * 32 + (k & 31)]; }
    Zb[i] = (u16)bf16r(v);
  }
  for (int i = t0; i < 8 * 512; i += st) {         // V1b: w1 [32,128]
    int j = i & 7, l = (i >> 3) & 63, nb = i >> 9;
    int k = 8 * (l >> 4) + j, c = 16 * nb + (l & 15);
    V1b[i] = (u16)bf16r(w1[k * FF + c]);
  }
  for (int i = t0; i < 8 * 512; i += st) {         // V2b: w2 [128,32]
    int j = i & 7, l = (i >> 3) & 63, kn = i >> 9;
    int kb = kn >> 1, nb2 = kn & 1;
    int k = 32 * kb + 8 * (l >> 4) + j, c = 16 * nb2 + (l & 15);
    V2b[i] = (u16)bf16r(w2[k * CC + c]);
  }
  for (int i = t0; i < 16 * 512; i += st) {        // WSb: Wstack [256,32]
    int j = i & 7, l = (i >> 3) & 63, kn = i >> 9; // Wstack[h*32+k][c]=W[k][h*32+c]
    int kb = kn >> 1, nb2 = kn & 1;
    int krow = kb * 32 + 8 * (l >> 4) + j;         // 0..255
    int h = krow >> 5, kk = krow & 31;
    int c = 16 * nb2 + (l & 15);
    WSb[i] = (u16)bf16r(W[kk * HC + h * 32 + c]);
  }
}

// ---------- K1C (fused): MFMA a-dots + int8 x -> combo  ||  8-replica histogram ----------
// combo row per node (16 dwords = 64B): [0..7] = (bf16 a_src | fp16 xscale) per head,
//                                       [8..15] = int8 x (32 bytes)
__global__ __launch_bounds__(256) void k1c(
    const float* __restrict__ x, const u16* __restrict__ Wb,
    const u16* __restrict__ Zb, const int* __restrict__ ei,
    unsigned* __restrict__ combo, float* __restrict__ a_d,
    int* __restrict__ deg8, unsigned* __restrict__ dstr, int n, int e, int nbc)
{
  if ((int)blockIdx.x >= nbc) {                    // histogram + rank role
    int bi = (int)blockIdx.x - nbc;
    int r = bi & (NR - 1);
    int* dr = deg8 + (size_t)r * n;
    int i = bi * 1024 + (int)threadIdx.x * 4;
    if (i >= e) return;
    const int* dst = ei + e;
    if (i + 3 < e) {
      int4 d4 = *(const int4*)(dst + i);
      unsigned r0 = (unsigned)atomicAdd(&dr[d4.x], 1);
      unsigned r1 = (unsigned)atomicAdd(&dr[d4.y], 1);
      unsigned r2 = (unsigned)atomicAdd(&dr[d4.z], 1);
      unsigned r3 = (unsigned)atomicAdd(&dr[d4.w], 1);
      uint4 o;
      o.x = (unsigned)d4.x | ((unsigned)r << 17) | (r0 << 20);
      o.y = (unsigned)d4.y | ((unsigned)r << 17) | (r1 << 20);
      o.z = (unsigned)d4.z | ((unsigned)r << 17) | (r2 << 20);
      o.w = (unsigned)d4.w | ((unsigned)r << 17) | (r3 << 20);
      *(uint4*)(dstr + i) = o;
    } else {
      for (int k = 0; k < 4 && i + k < e; ++k) {
        int d = dst[i + k];
        unsigned rr = (unsigned)atomicAdd(&dr[d], 1);
        dstr[i + k] = (unsigned)d | ((unsigned)r << 17) | (rr << 20);
      }
    }
    return;
  }
  __shared__ u16 lt[4][16 * 264];                  // per-wave [16 rows][264 halfs]
  int wid = threadIdx.x >> 6, lane = threadIdx.x & 63;
  int q = lane & 15, g = lane >> 4;
  long node0 = (long)((int)blockIdx.x * 4 + wid) * 16;
  if (node0 + 16 > n) node0 = n - 16;              // overlap tail: duplicate identical writes
  u16* L = lt[wid];
  u16* combo16 = (u16*)combo;

  // A-frag: x[node0+q][8g..8g+7] -> bf16; keep fp32 copies for quantization
  const float* xr = x + (node0 + q) * CC + 8 * g;
  float4 xa = *(const float4*)xr, xb = *(const float4*)(xr + 4);
  bf16x8 af;
  af[0] = (short)bf16r(xa.x); af[1] = (short)bf16r(xa.y);
  af[2] = (short)bf16r(xa.z); af[3] = (short)bf16r(xa.w);
  af[4] = (short)bf16r(xb.x); af[5] = (short)bf16r(xb.y);
  af[6] = (short)bf16r(xb.z); af[7] = (short)bf16r(xb.w);

  // ---- per-node x absmax over 32 ch (4 lanes share q: xor 16, 32) ----
  float mx = fmaxf(fmaxf(fmaxf(fabsf(xa.x), fabsf(xa.y)), fmaxf(fabsf(xa.z), fabsf(xa.w))),
                   fmaxf(fmaxf(fabsf(xb.x), fabsf(xb.y)), fmaxf(fabsf(xb.z), fabsf(xb.w))));
  mx = fmaxf(mx, __shfl_xor(mx, 16));
  mx = fmaxf(mx, __shfl_xor(mx, 32));
  float rinv = (mx > 0.f) ? 127.f / mx : 0.f;
  u16 sch = f2h(mx * (1.f / 127.f));
  combo16[((node0 + q) * 16 + 2 * g) * 2 + 1]     = sch;
  combo16[((node0 + q) * 16 + 2 * g + 1) * 2 + 1] = sch;
  {
    int q0 = min(max(__float2int_rn(xa.x * rinv), -127), 127) + 128;
    int q1 = min(max(__float2int_rn(xa.y * rinv), -127), 127) + 128;
    int q2 = min(max(__float2int_rn(xa.z * rinv), -127), 127) + 128;
    int q3 = min(max(__float2int_rn(xa.w * rinv), -127), 127) + 128;
    int q4 = min(max(__float2int_rn(xb.x * rinv), -127), 127) + 128;
    int q5 = min(max(__float2int_rn(xb.y * rinv), -127), 127) + 128;
    int q6 = min(max(__float2int_rn(xb.z * rinv), -127), 127) + 128;
    int q7 = min(max(__float2int_rn(xb.w * rinv), -127), 127) + 128;
    uint2 pk;
    pk.x = (unsigned)q0 | ((unsigned)q1 << 8) | ((unsigned)q2 << 16) | ((unsigned)q3 << 24);
    pk.y = (unsigned)q4 | ((unsigned)q5 << 8) | ((unsigned)q6 << 16) | ((unsigned)q7 << 24);
    *(uint2*)(combo + (node0 + q) * 16 + 8 + 2 * g) = pk;
  }

  // ---- xp = x@W into LDS (needed only for the a-dots) ----
#pragma unroll
  for (int nb = 0; nb < 16; ++nb) {
    bf16x8 bf = *(const bf16x8*)(Wb + nb * 512 + lane * 8);
    f32x4 acc = {0.f, 0.f, 0.f, 0.f};
    acc = __builtin_amdgcn_mfma_f32_16x16x32_bf16(af, bf, acc, 0, 0, 0);
    int col = 16 * nb + q;
#pragma unroll
    for (int r = 0; r < 4; ++r)
      L[(4 * g + r) * 264 + col] = (u16)bf16r(acc[r]);
  }
  __syncthreads();

  // a_src/a_dst: [16 nodes,256] x [256,16] via 8 chained mfma
  f32x4 az = {0.f, 0.f, 0.f, 0.f};
#pragma unroll
  for (int kb = 0; kb < 8; ++kb) {
    bf16x8 a2 = *(const bf16x8*)(L + q * 264 + kb * 32 + g * 8);
    bf16x8 zb = *(const bf16x8*)(Zb + kb * 512 + lane * 8);
    az = __builtin_amdgcn_mfma_f32_16x16x32_bf16(a2, zb, az, 0, 0, 0);
  }
  int hq = q & 7;
  if (q < 8) {                                     // a_src -> combo lo16 (bf16)
#pragma unroll
    for (int r = 0; r < 4; ++r)
      combo16[((node0 + 4 * g + r) * 16 + hq) * 2] = (u16)bf16r(az[r]);
  } else {                                         // a_dst (fp32)
#pragma unroll
    for (int r = 0; r < 4; ++r)
      a_d[(node0 + 4 * g + r) * HH + hq] = az[r];
  }
}

// ---------- scan phase A: per-1024-block sums (over NR replicas) ----------
__global__ __launch_bounds__(256) void kscanA(const int* __restrict__ deg8,
                                              int* __restrict__ bsum, int n)
{
  __shared__ int ws[4];
  int t = threadIdx.x;
  int i = (int)blockIdx.x * 1024 + t * 4;
  int s = 0;
  if (i + 3 < n) {
#pragma unroll
    for (int r = 0; r < NR; ++r) {
      int4 v = *(const int4*)(deg8 + (size_t)r * n + i);
      s += v.x + v.y + v.z + v.w;
    }
  } else {
    for (int k = 0; k < 4 && i + k < n; ++k)
#pragma unroll
      for (int r = 0; r < NR; ++r) s += deg8[(size_t)r * n + i + k];
  }
#pragma unroll
  for (int mask = 1; mask < 64; mask <<= 1) s += __shfl_xor(s, mask);
  if ((t & 63) == 0) ws[t >> 6] = s;
  __syncthreads();
  if (t == 0) bsum[blockIdx.x] = ws[0] + ws[1] + ws[2] + ws[3];
}

// ---------- scan phase B ----------
__global__ __launch_bounds__(1024) void kscanB(int* __restrict__ bsum, int nb)
{
  __shared__ int wsum[16];
  int t = threadIdx.x, lane = t & 63, wid = t >> 6;
  int v = (t < nb) ? bsum[t] : 0;
  int s = v;
#pragma unroll
  for (int d = 1; d < 64; d <<= 1) { int tt = __shfl_up(s, d); if (lane >= d) s += tt; }
  if (lane == 63) wsum[wid] = s;
  __syncthreads();
  if (wid == 0) {
    int w = (lane < 16) ? wsum[lane] : 0;
#pragma unroll
    for (int d = 1; d < 16; d <<= 1) { int tt = __shfl_up(w, d); if (lane >= d) w += tt; }
    if (lane < 16) wsum[lane] = w;
  }
  __syncthreads();
  int excl = s - v + ((wid > 0) ? wsum[wid - 1] : 0);
  if (t < nb) bsum[t] = excl;
}

// ---------- scan phase C: per-replica bases rb[0..NR-1] + degt ----------
__global__ __launch_bounds__(256) void kscanC(const int* __restrict__ deg8,
                                              const int* __restrict__ bsum,
                                              int* __restrict__ rb,
                                              int* __restrict__ degt, int n)
{
  __shared__ int ws[4];
  int t = threadIdx.x, lane = t & 63, wid = t >> 6;
  int i = (int)blockIdx.x * 1024 + t * 4;
  int cr[NR][4];
#pragma unroll
  for (int r = 0; r < NR; ++r) {
    if (i + 3 < n) {
      int4 v = *(const int4*)(deg8 + (size_t)r * n + i);
      cr[r][0] = v.x; cr[r][1] = v.y; cr[r][2] = v.z; cr[r][3] = v.w;
    } else {
      for (int k = 0; k < 4; ++k)
        cr[r][k] = (i + k < n) ? deg8[(size_t)r * n + i + k] : 0;
    }
  }
  int tot[4];
#pragma unroll
  for (int k = 0; k < 4; ++k) {
    int s = 0;
#pragma unroll
    for (int r = 0; r < NR; ++r) s += cr[r][k];
    tot[k] = s;
  }
  int tsum = tot[0] + tot[1] + tot[2] + tot[3];
  int s = tsum;
#pragma unroll
  for (int d = 1; d < 64; d <<= 1) { int tt = __shfl_up(s, d); if (lane >= d) s += tt; }
  if (lane == 63) ws[wid] = s;
  __syncthreads();
  if (t == 0) {
    int a = ws[0]; ws[0] = 0;
    int b = ws[1]; ws[1] = a; a += b;
    int c = ws[2]; ws[2] = a; a += c;
    ws[3] = a;
  }
  __syncthreads();
  int base = bsum[blockIdx.x] + ws[wid] + (s - tsum);
#pragma unroll
  for (int k = 0; k < 4; ++k) {
    if (i + k < n) {
      int b0 = base;
#pragma unroll
      for (int r = 0; r < NR; ++r) {
        rb[(size_t)r * n + i + k] = b0;
        b0 += cr[r][k];
      }
      degt[i + k] = tot[k];
    }
    base += tot[k];
  }
}

// ---------- CSR scatter: rank-based, ATOMIC-FREE, dst-quadrant L2-local writes ----------
__global__ __launch_bounds__(256) void kscatter(
    const int* __restrict__ ei, const unsigned* __restrict__ dstr, int e,
    const int* __restrict__ rb, int* __restrict__ csr, int n)
{
  int oct = (int)blockIdx.x & 3;
  int nsub = (int)gridDim.x >> 2;
  int sub = (int)blockIdx.x >> 2;
  int nper = (n + 3) >> 2;
  int lo = oct * nper, hi = lo + nper;
  int stride = nsub << 10;
  for (int i = (sub * 256 + (int)threadIdx.x) * 4; i < e; i += stride) {
    if (i + 3 < e) {
      uint4 d4 = *(const uint4*)(dstr + i);
      int4 s4 = *(const int4*)(ei + i);
      int dx = d4.x & 0x1ffff, dy = d4.y & 0x1ffff,
          dz = d4.z & 0x1ffff, dw = d4.w & 0x1ffff;
      if (dx >= lo && dx < hi)
        csr[rb[(size_t)((d4.x >> 17) & 7) * n + dx] + (d4.x >> 20)] = s4.x;
      if (dy >= lo && dy < hi)
        csr[rb[(size_t)((d4.y >> 17) & 7) * n + dy] + (d4.y >> 20)] = s4.y;
      if (dz >= lo && dz < hi)
        csr[rb[(size_t)((d4.z >> 17) & 7) * n + dz] + (d4.z >> 20)] = s4.z;
      if (dw >= lo && dw < hi)
        csr[rb[(size_t)((d4.w >> 17) & 7) * n + dw] + (d4.w >> 20)] = s4.w;
    } else {
      for (int k = 0; k < 4 && i + k < e; ++k) {
        unsigned dv = dstr[i + k];
        int d = dv & 0x1ffff;
        if (d >= lo && d < hi)
          csr[rb[(size_t)((dv >> 17) & 7) * n + d] + (dv >> 20)] = ei[i + k];
      }
    }
  }
}

// ---------- KAGG: raw-x aggregation (round-16 form) + pipelined A-phase gathers ----------
// A-layout: eg=lane>>3 (edge slot), ha=lane&7 (head). B-layout: hb=eg, c4=lane&7.
// Next chunk's csr + combo gathers are issued BEFORE the current chunk's B-phase,
// hiding their latency under the unrolled 8-edge fma block.
__global__ __launch_bounds__(256) void kagg(
    const int* __restrict__ csr, const int* __restrict__ offs,
    const int* __restrict__ degt,
    const unsigned* __restrict__ combo, const float* __restrict__ a_d,
    unsigned* __restrict__ agg32, int n)
{
  int lane = threadIdx.x & 63;
  int wid  = threadIdx.x >> 6;
  int base = ((int)blockIdx.x * 4 + wid) * 4;      // 4 nodes per wave
  int eg = lane >> 3, ha = lane & 7;
  int hb = eg;
  int c4 = lane & 7;

  for (int t = 0; t < 4; ++t) {
    int node = base + t;
    if (node >= n) return;
    int start = offs[node];
    int dg = degt[node];
    unsigned aw_self = combo[(size_t)node * 16 + ha];
    float ad_a  = a_d[(size_t)node * HH + ha];
    float aself = leaky(bflo(aw_self) + ad_a);

    float acc0 = 0.f, acc1 = 0.f, acc2 = 0.f, acc3 = 0.f;
    float dnA = 0.f, osA = 0.f;

    // prologue: gather chunk 0
    bool vn = eg < dg;
    int srcl_n = vn ? csr[start + eg] : 0;
    unsigned av_n = vn ? combo[(size_t)srcl_n * 16 + ha] : 0u;

    for (int j0 = 0; j0 < dg; j0 += 8) {
      int cnt = dg - j0; if (cnt > 8) cnt = 8;
      bool valid = vn;
      int srcl = srcl_n;
      unsigned av = av_n;
      // prefetch next chunk (overlaps this chunk's B-phase)
      int idx2 = j0 + 8 + eg;
      vn = idx2 < dg;
      srcl_n = vn ? csr[start + idx2] : 0;
      av_n = vn ? combo[(size_t)srcl_n * 16 + ha] : 0u;

      float pw = 0.f;
      if (valid) {
        float al = leaky(bflo(av) + ad_a);
        float p  = __expf(al - aself);
        pw = p * h2f(av >> 16);                    // p * xscale_src
        dnA += p; osA += pw;
      }
      if (cnt == 8) {
#pragma unroll
        for (int j = 0; j < 8; ++j) {
          int sl = (j << 3) + hb;
          float wt = __shfl(pw, sl);
          int s = __shfl(srcl, sl);
          unsigned w = combo[(size_t)s * 16 + 8 + c4]; // second half — L2-hot
          acc0 = fmaf(ub0(w), wt, acc0);
          acc1 = fmaf(ub1(w), wt, acc1);
          acc2 = fmaf(ub2(w), wt, acc2);
          acc3 = fmaf(ub3(w), wt, acc3);
        }
      } else {
        for (int j = 0; j < cnt; ++j) {
          int sl = (j << 3) + hb;
          float wt = __shfl(pw, sl);
          int s = __shfl(srcl, sl);
          unsigned w = combo[(size_t)s * 16 + 8 + c4];
          acc0 = fmaf(ub0(w), wt, acc0);
          acc1 = fmaf(ub1(w), wt, acc1);
          acc2 = fmaf(ub2(w), wt, acc2);
          acc3 = fmaf(ub3(w), wt, acc3);
        }
      }
    }

    // reduce dn/osum over edge-slot dim (eg): after this, value is per-head ha
    float dnH = dnA, osH = osA;
    dnH += __shfl_xor(dnH, 8);  osH += __shfl_xor(osH, 8);
    dnH += __shfl_xor(dnH, 16); osH += __shfl_xor(osH, 16);
    dnH += __shfl_xor(dnH, 32); osH += __shfl_xor(osH, 32);
    float dnB = __shfl(dnH, hb);
    float osB = __shfl(osH, hb);
    float scB = __shfl(h2f(aw_self >> 16), hb);    // xscale_node (replicated)

    // self loop: p = 1
    {
      unsigned w = combo[(size_t)node * 16 + 8 + c4];
      dnB += 1.f; osB += scB;
      acc0 = fmaf(ub0(w), scB, acc0);
      acc1 = fmaf(ub1(w), scB, acc1);
      acc2 = fmaf(ub2(w), scB, acc2);
      acc3 = fmaf(ub3(w), scB, acc3);
    }

    float corr = -128.f * osB;
    float inv = 0.125f / dnB;                      // fold 1/8 head-mean here
    acc0 = (acc0 + corr) * inv;
    acc1 = (acc1 + corr) * inv;
    acc2 = (acc2 + corr) * inv;
    acc3 = (acc3 + corr) * inv;
    uint2 pk;
    pk.x = bf16r(acc0) | (bf16r(acc1) << 16);
    pk.y = bf16r(acc2) | (bf16r(acc3) << 16);
    *(uint2*)(agg32 + (size_t)node * 128 + hb * 16 + c4 * 2) = pk;
  }
}

// ---------- K5M: MFMA tail — og = agg@Wstack, + x + bg, LN1 + FFN(mfma) + LN2 ----------
__global__ __launch_bounds__(256) void k5m(
    const u16* __restrict__ agg16, const float* __restrict__ x,
    const float* __restrict__ bg, const u16* __restrict__ WSb,
    const u16* __restrict__ V1b, const u16* __restrict__ V2b,
    const float* __restrict__ b1, const float* __restrict__ b2,
    const float* __restrict__ g1, const float* __restrict__ be1,
    const float* __restrict__ g2, const float* __restrict__ be2,
    float* __restrict__ out, int n)
{
  __shared__ u16   lh[4][16 * 40];
  __shared__ u16   lf[4][16 * 136];
  __shared__ float lo[4][16 * 36];
  int wid = threadIdx.x >> 6, lane = threadIdx.x & 63;
  int q = lane & 15, g = lane >> 4;
  long node0 = (long)((int)blockIdx.x * 4 + wid) * 16;
  if (node0 + 16 > n) node0 = n - 16;
  u16* LH = lh[wid]; u16* LF = lf[wid]; float* LO = lo[wid];

  // stage x + bg cooperatively
  {
    int row = lane >> 2, off = (lane & 3) * 8;
    const float* x8 = x + (node0 + row) * CC + off;
    float4 c0 = *(const float4*)x8, c1 = *(const float4*)(x8 + 4);
    float4 bg0 = *(const float4*)(bg + off), bg1 = *(const float4*)(bg + off + 4);
    float4 s0 = make_float4(c0.x + bg0.x, c0.y + bg0.y, c0.z + bg0.z, c0.w + bg0.w);
    float4 s1 = make_float4(c1.x + bg1.x, c1.y + bg1.y, c1.z + bg1.z, c1.w + bg1.w);
    *(float4*)(LO + row * 36 + off)     = s0;
    *(float4*)(LO + row * 36 + off + 4) = s1;
  }
  __syncthreads();

  // og = agg @ Wstack  ([16,256] x [256,32]) then LO += og
  {
    f32x4 a20 = {0.f, 0.f, 0.f, 0.f}, a21 = {0.f, 0.f, 0.f, 0.f};
#pragma unroll
    for (int kb = 0; kb < 8; ++kb) {
      bf16x8 af = *(const bf16x8*)(agg16 + (node0 + q) * 256 + kb * 32 + g * 8);
      bf16x8 w0 = *(const bf16x8*)(WSb + (kb * 2 + 0) * 512 + lane * 8);
      bf16x8 w1v = *(const bf16x8*)(WSb + (kb * 2 + 1) * 512 + lane * 8);
      a20 = __builtin_amdgcn_mfma_f32_16x16x32_bf16(af, w0, a20, 0, 0, 0);
      a21 = __builtin_amdgcn_mfma_f32_16x16x32_bf16(af, w1v, a21, 0, 0, 0);
    }
#pragma unroll
    for (int r = 0; r < 4; ++r) {
      LO[(4 * g + r) * 36 + q]      += a20[r];
      LO[(4 * g + r) * 36 + 16 + q] += a21[r];
    }
  }
  __syncthreads();

  float hv[32];
  if (lane < 16) {
#pragma unroll
    for (int i = 0; i < 8; ++i) {
      float4 t = *(const float4*)(LO + q * 36 + i * 4);
      hv[4*i] = t.x; hv[4*i+1] = t.y; hv[4*i+2] = t.z; hv[4*i+3] = t.w;
    }
    float mu = 0.f;
#pragma unroll
    for (int c = 0; c < 32; ++c) mu += hv[c];
    mu *= (1.f / 32.f);
    float var = 0.f;
#pragma unroll
    for (int c = 0; c < 32; ++c) { float t = hv[c] - mu; var = fmaf(t, t, var); }
    float rs = rsqrtf(var * (1.f / 32.f) + LNEPS);
#pragma unroll
    for (int c = 0; c < 32; ++c) hv[c] = (hv[c] - mu) * rs * g1[c] + be1[c];
    uint* dst = (uint*)(LH + q * 40);
#pragma unroll
    for (int i = 0; i < 16; ++i)
      dst[i] = bf16r(hv[2*i]) | (bf16r(hv[2*i+1]) << 16);
  }
  __syncthreads();

  bf16x8 ah = *(const bf16x8*)(LH + q * 40 + g * 8);
#pragma unroll
  for (int nb = 0; nb < 8; ++nb) {
    bf16x8 v1 = *(const bf16x8*)(V1b + nb * 512 + lane * 8);
    f32x4 acc = {0.f, 0.f, 0.f, 0.f};
    acc = __builtin_amdgcn_mfma_f32_16x16x32_bf16(ah, v1, acc, 0, 0, 0);
    int col = 16 * nb + q;
    float bias = b1[col];
#pragma unroll
    for (int r = 0; r < 4; ++r) {
      float f = fmaxf(acc[r] + bias, 0.f);
      LF[(4 * g + r) * 136 + col] = (u16)bf16r(f);
    }
  }
  __syncthreads();

  f32x4 a20 = {0.f, 0.f, 0.f, 0.f}, a21 = {0.f, 0.f, 0.f, 0.f};
#pragma unroll
  for (int kb = 0; kb < 4; ++kb) {
    bf16x8 af2 = *(const bf16x8*)(LF + q * 136 + kb * 32 + g * 8);
    bf16x8 v20 = *(const bf16x8*)(V2b + (kb * 2 + 0) * 512 + lane * 8);
    bf16x8 v21 = *(const bf16x8*)(V2b + (kb * 2 + 1) * 512 + lane * 8);
    a20 = __builtin_amdgcn_mfma_f32_16x16x32_bf16(af2, v20, a20, 0, 0, 0);
    a21 = __builtin_amdgcn_mfma_f32_16x16x32_bf16(af2, v21, a21, 0, 0, 0);
  }
  __syncthreads();
#pragma unroll
  for (int r = 0; r < 4; ++r) {
    LO[(4 * g + r) * 36 + q]      = a20[r];
    LO[(4 * g + r) * 36 + 16 + q] = a21[r];
  }
  __syncthreads();

  if (lane < 16) {
    float ov[32];
#pragma unroll
    for (int i = 0; i < 8; ++i) {
      float4 t = *(const float4*)(LO + q * 36 + i * 4);
      ov[4*i] = t.x; ov[4*i+1] = t.y; ov[4*i+2] = t.z; ov[4*i+3] = t.w;
    }
#pragma unroll
    for (int c = 0; c < 32; ++c) ov[c] += b2[c] + hv[c];
    float mu2 = 0.f;
#pragma unroll
    for (int c = 0; c < 32; ++c) mu2 += ov[c];
    mu2 *= (1.f / 32.f);
    float var2 = 0.f;
#pragma unroll
    for (int c = 0; c < 32; ++c) { float t = ov[c] - mu2; var2 = fmaf(t, t, var2); }
    float rs2 = rsqrtf(var2 * (1.f / 32.f) + LNEPS);
    float* op = out + (node0 + q) * CC;
#pragma unroll
    for (int i = 0; i < 8; ++i) {
      float4 o;
      o.x = (ov[4*i]   - mu2) * rs2 * g2[4*i]   + be2[4*i];
      o.y = (ov[4*i+1] - mu2) * rs2 * g2[4*i+1] + be2[4*i+1];
      o.z = (ov[4*i+2] - mu2) * rs2 * g2[4*i+2] + be2[4*i+2];
      o.w = (ov[4*i+3] - mu2) * rs2 * g2[4*i+3] + be2[4*i+3];
      *(float4*)(op + i * 4) = o;
    }
  }
}

// ---------- launch ----------
extern "C" void kernel_launch(void* const* d_in, const int* in_sizes, int n_in,
                              void* d_out, int out_size, void* d_ws, size_t ws_size,
                              hipStream_t stream)
{
  const float* x    = (const float*)d_in[0];
  const int*   ei   = (const int*)d_in[1];
  const float* W    = (const float*)d_in[2];
  const float* atts = (const float*)d_in[3];
  const float* attd = (const float*)d_in[4];
  const float* bg   = (const float*)d_in[5];
  const float* w1   = (const float*)d_in[6];
  const float* b1   = (const float*)d_in[7];
  const float* w2   = (const float*)d_in[8];
  const float* b2   = (const float*)d_in[9];
  const float* g1   = (const float*)d_in[10];
  const float* be1  = (const float*)d_in[11];
  const float* g2   = (const float*)d_in[12];
  const float* be2  = (const float*)d_in[13];

  int n = in_sizes[0] / CC;
  int e = in_sizes[1] / 2;

  uint8_t* ws = (uint8_t*)d_ws;
  size_t o = 0;
  unsigned* combo = (unsigned*)(ws + o); o += (size_t)n * 64;    // 64B/node: ascp+xqx
  float* a_d = (float*)(ws + o); o += (size_t)n * HH * 4;
  unsigned* agg32 = (unsigned*)(ws + o); o += (size_t)n * 512;   // bf16 agg [N,256]
  int* deg8   = (int*)(ws + o); o += (size_t)n * NR * 4;
  int* rb     = (int*)(ws + o); o += (size_t)n * NR * 4;
  int* degt   = (int*)(ws + o); o += (size_t)n * 4;
  unsigned* dstr = (unsigned*)(ws + o); o += (size_t)e * 4;
  int* csr    = (int*)(ws + o); o += (size_t)e * 4;
  int* bsum   = (int*)(ws + o); o += 4096;
  u16* Wb  = (u16*)(ws + o); o += 16 * 512 * 2;
  u16* Zb  = (u16*)(ws + o); o += 8 * 512 * 2;
  u16* V1b = (u16*)(ws + o); o += 8 * 512 * 2;
  u16* V2b = (u16*)(ws + o); o += 8 * 512 * 2;
  u16* WSb = (u16*)(ws + o); o += 16 * 512 * 2;

  (void)hipMemsetAsync(deg8, 0, (size_t)n * NR * 4, stream);

  int nwaves = (n + 15) / 16;
  int nbc   = (nwaves + 3) / 4;
  int nb_e4 = (e + 1023) / 1024;
  int nb_s  = (n + 1023) / 1024;
  int nb_ag = (n + 15) / 16;        // 4 waves x 4 nodes = 16 nodes per block

  klayout <<<16, 256, 0, stream>>>(W, atts, attd, w1, w2, Wb, Zb, V1b, V2b, WSb);
  k1c     <<<nbc + nb_e4, 256, 0, stream>>>(x, Wb, Zb, ei, combo, a_d, deg8,
                                            dstr, n, e, nbc);
  kscanA  <<<nb_s, 256, 0, stream>>>(deg8, bsum, n);
  kscanB  <<<1, 1024, 0, stream>>>(bsum, nb_s);
  kscanC  <<<nb_s, 256, 0, stream>>>(deg8, bsum, rb, degt, n);
  kscatter<<<512, 256, 0, stream>>>(ei, dstr, e, rb, csr, n);
  kagg    <<<nb_ag, 256, 0, stream>>>(csr, rb, degt, combo, a_d, agg32, n);
  k5m     <<<nbc, 256, 0, stream>>>((const u16*)agg32, x, bg, WSb, V1b, V2b,
                                    b1, b2, g1, be1, g2, be2, (float*)d_out, n);
}

// Round 19
// 216.455 us; speedup vs baseline: 1.1245x; 1.0110x over previous
//
#include <hip/hip_runtime.h>
#include <hip/hip_fp16.h>
#include <stdint.h>

#define HH 8
#define CC 32
#define HC 256   // H*C
#define FF 128
#define NEG 0.2f
#define LNEPS 1e-5f
#define NR 8     // histogram replicas

typedef __attribute__((ext_vector_type(8))) short bf16x8;
typedef __attribute__((ext_vector_type(4))) float f32x4;
typedef unsigned short u16;

// ---------- helpers ----------
__device__ inline unsigned bf16r(float f) {           // round-to-nearest-even bf16
  unsigned u = __float_as_uint(f);
  return (u + 0x7fffu + ((u >> 16) & 1u)) >> 16;
}
__device__ inline float bflo(unsigned w) { return __uint_as_float(w << 16); }
__device__ inline float bfhi(unsigned w) { return __uint_as_float(w & 0xffff0000u); }
__device__ inline float leaky(float v) { return v >= 0.f ? v : NEG * v; }
__device__ inline float h2f(unsigned hbits) {
  return __half2float(__ushort_as_half((unsigned short)hbits));
}
__device__ inline u16 f2h(float f) {
  return __half_as_ushort(__float2half(f));
}
// byte extract -> float (v_cvt_f32_ubyte0..3)
__device__ inline float ub0(unsigned w) { return (float)(w & 0xffu); }
__device__ inline float ub1(unsigned w) { return (float)((w >> 8) & 0xffu); }
__device__ inline float ub2(unsigned w) { return (float)((w >> 16) & 0xffu); }
__device__ inline float ub3(unsigned w) { return (float)(w >> 24); }

// ---------- KLAYOUT: weight repack (bf16) + fused attention-dot matrix Wz ----------
__global__ __launch_bounds__(256) void klayout(
    const float* __restrict__ W, const float* __restrict__ atts,
    const float* __restrict__ attd, const float* __restrict__ w1,
    const float* __restrict__ w2,
    u16* __restrict__ Zb2, u16* __restrict__ V1b,
    u16* __restrict__ V2b, u16* __restrict__ WSb)
{
  int t0 = (int)blockIdx.x * 256 + (int)threadIdx.x;
  int st = (int)gridDim.x * 256;
  // Zb2: [32,16] Wz in B-frag layout; Wz[k][tc] = sum_c W[k][(tc&7)*32+c]*att[tc][c]
  for (int i = t0; i < 512; i += st) {
    int j = i & 7, l = i >> 3;
    int k = 8 * (l >> 4) + j, tc = l & 15;
    const float* av = (tc < 8) ? (atts + tc * 32) : (attd + (tc - 8) * 32);
    const float* wr = W + k * HC + (tc & 7) * 32;
    float s = 0.f;
#pragma unroll
    for (int c = 0; c < 32; ++c) s = fmaf(wr[c], av[c], s);
    Zb2[i] = (u16)bf16r(s);
  }
  for (int i = t0; i < 8 * 512; i += st) {         // V1b: w1 [32,128]
    int j = i & 7, l = (i >> 3) & 63, nb = i >> 9;
    int k = 8 * (l >> 4) + j, c = 16 * nb + (l & 15);
    V1b[i] = (u16)bf16r(w1[k * FF + c]);
  }
  for (int i = t0; i < 8 * 512; i += st) {         // V2b: w2 [128,32]
    int j = i & 7, l = (i >> 3) & 63, kn = i >> 9;
    int kb = kn >> 1, nb2 = kn & 1;
    int k = 32 * kb + 8 * (l >> 4) + j, c = 16 * nb2 + (l & 15);
    V2b[i] = (u16)bf16r(w2[k * CC + c]);
  }
  for (int i = t0; i < 16 * 512; i += st) {        // WSb: Wstack [256,32]
    int j = i & 7, l = (i >> 3) & 63, kn = i >> 9; // Wstack[h*32+k][c]=W[k][h*32+c]
    int kb = kn >> 1, nb2 = kn & 1;
    int krow = kb * 32 + 8 * (l >> 4) + j;         // 0..255
    int h = krow >> 5, kk = krow & 31;
    int c = 16 * nb2 + (l & 15);
    WSb[i] = (u16)bf16r(W[kk * HC + h * 32 + c]);
  }
}

// ---------- K1C (fused, ZERO LDS): a-dots via one MFMA + int8 x -> combo || histogram ----------
// combo row per node (16 dwords = 64B): [0..7] = (bf16 a_src | fp16 xscale) per head,
//                                       [8..15] = int8 x (32 bytes)
__global__ __launch_bounds__(256) void k1c(
    const float* __restrict__ x, const u16* __restrict__ Zb2,
    const int* __restrict__ ei,
    unsigned* __restrict__ combo, float* __restrict__ a_d,
    int* __restrict__ deg8, unsigned* __restrict__ dstr, int n, int e, int nbc)
{
  if ((int)blockIdx.x >= nbc) {                    // histogram + rank role
    int bi = (int)blockIdx.x - nbc;
    int r = bi & (NR - 1);
    int* dr = deg8 + (size_t)r * n;
    int i = bi * 1024 + (int)threadIdx.x * 4;
    if (i >= e) return;
    const int* dst = ei + e;
    if (i + 3 < e) {
      int4 d4 = *(const int4*)(dst + i);
      unsigned r0 = (unsigned)atomicAdd(&dr[d4.x], 1);
      unsigned r1 = (unsigned)atomicAdd(&dr[d4.y], 1);
      unsigned r2 = (unsigned)atomicAdd(&dr[d4.z], 1);
      unsigned r3 = (unsigned)atomicAdd(&dr[d4.w], 1);
      uint4 o;
      o.x = (unsigned)d4.x | ((unsigned)r << 17) | (r0 << 20);
      o.y = (unsigned)d4.y | ((unsigned)r << 17) | (r1 << 20);
      o.z = (unsigned)d4.z | ((unsigned)r << 17) | (r2 << 20);
      o.w = (unsigned)d4.w | ((unsigned)r << 17) | (r3 << 20);
      *(uint4*)(dstr + i) = o;
    } else {
      for (int k = 0; k < 4 && i + k < e; ++k) {
        int d = dst[i + k];
        unsigned rr = (unsigned)atomicAdd(&dr[d], 1);
        dstr[i + k] = (unsigned)d | ((unsigned)r << 17) | (rr << 20);
      }
    }
    return;
  }
  int wid = threadIdx.x >> 6, lane = threadIdx.x & 63;
  int q = lane & 15, g = lane >> 4;
  long node0 = (long)((int)blockIdx.x * 4 + wid) * 16;
  if (node0 + 16 > n) node0 = n - 16;              // overlap tail: duplicate identical writes
  u16* combo16 = (u16*)combo;

  // A-frag: x[node0+q][8g..8g+7] -> bf16; keep fp32 copies for quantization
  const float* xr = x + (node0 + q) * CC + 8 * g;
  float4 xa = *(const float4*)xr, xb = *(const float4*)(xr + 4);
  bf16x8 af;
  af[0] = (short)bf16r(xa.x); af[1] = (short)bf16r(xa.y);
  af[2] = (short)bf16r(xa.z); af[3] = (short)bf16r(xa.w);
  af[4] = (short)bf16r(xb.x); af[5] = (short)bf16r(xb.y);
  af[6] = (short)bf16r(xb.z); af[7] = (short)bf16r(xb.w);

  // ---- per-node x absmax over 32 ch (4 lanes share q: xor 16, 32) ----
  float mx = fmaxf(fmaxf(fmaxf(fabsf(xa.x), fabsf(xa.y)), fmaxf(fabsf(xa.z), fabsf(xa.w))),
                   fmaxf(fmaxf(fabsf(xb.x), fabsf(xb.y)), fmaxf(fabsf(xb.z), fabsf(xb.w))));
  mx = fmaxf(mx, __shfl_xor(mx, 16));
  mx = fmaxf(mx, __shfl_xor(mx, 32));
  float rinv = (mx > 0.f) ? 127.f / mx : 0.f;
  u16 sch = f2h(mx * (1.f / 127.f));
  combo16[((node0 + q) * 16 + 2 * g) * 2 + 1]     = sch;
  combo16[((node0 + q) * 16 + 2 * g + 1) * 2 + 1] = sch;
  {
    int q0 = min(max(__float2int_rn(xa.x * rinv), -127), 127) + 128;
    int q1 = min(max(__float2int_rn(xa.y * rinv), -127), 127) + 128;
    int q2 = min(max(__float2int_rn(xa.z * rinv), -127), 127) + 128;
    int q3 = min(max(__float2int_rn(xa.w * rinv), -127), 127) + 128;
    int q4 = min(max(__float2int_rn(xb.x * rinv), -127), 127) + 128;
    int q5 = min(max(__float2int_rn(xb.y * rinv), -127), 127) + 128;
    int q6 = min(max(__float2int_rn(xb.z * rinv), -127), 127) + 128;
    int q7 = min(max(__float2int_rn(xb.w * rinv), -127), 127) + 128;
    uint2 pk;
    pk.x = (unsigned)q0 | ((unsigned)q1 << 8) | ((unsigned)q2 << 16) | ((unsigned)q3 << 24);
    pk.y = (unsigned)q4 | ((unsigned)q5 << 8) | ((unsigned)q6 << 16) | ((unsigned)q7 << 24);
    *(uint2*)(combo + (node0 + q) * 16 + 8 + 2 * g) = pk;
  }

  // ---- a_src/a_dst: one MFMA [16,32]x[32,16] with precomputed Wz ----
  bf16x8 zb = *(const bf16x8*)(Zb2 + lane * 8);
  f32x4 az = {0.f, 0.f, 0.f, 0.f};
  az = __builtin_amdgcn_mfma_f32_16x16x32_bf16(af, zb, az, 0, 0, 0);
  int hq = q & 7;
  if (q < 8) {                                     // a_src -> combo lo16 (bf16)
#pragma unroll
    for (int r = 0; r < 4; ++r)
      combo16[((node0 + 4 * g + r) * 16 + hq) * 2] = (u16)bf16r(az[r]);
  } else {                                         // a_dst (fp32)
#pragma unroll
    for (int r = 0; r < 4; ++r)
      a_d[(node0 + 4 * g + r) * HH + hq] = az[r];
  }
}

// ---------- scan phase A: per-1024-block sums (over NR replicas) ----------
__global__ __launch_bounds__(256) void kscanA(const int* __restrict__ deg8,
                                              int* __restrict__ bsum, int n)
{
  __shared__ int ws[4];
  int t = threadIdx.x;
  int i = (int)blockIdx.x * 1024 + t * 4;
  int s = 0;
  if (i + 3 < n) {
#pragma unroll
    for (int r = 0; r < NR; ++r) {
      int4 v = *(const int4*)(deg8 + (size_t)r * n + i);
      s += v.x + v.y + v.z + v.w;
    }
  } else {
    for (int k = 0; k < 4 && i + k < n; ++k)
#pragma unroll
      for (int r = 0; r < NR; ++r) s += deg8[(size_t)r * n + i + k];
  }
#pragma unroll
  for (int mask = 1; mask < 64; mask <<= 1) s += __shfl_xor(s, mask);
  if ((t & 63) == 0) ws[t >> 6] = s;
  __syncthreads();
  if (t == 0) bsum[blockIdx.x] = ws[0] + ws[1] + ws[2] + ws[3];
}

// ---------- scan phase B ----------
__global__ __launch_bounds__(1024) void kscanB(int* __restrict__ bsum, int nb)
{
  __shared__ int wsum[16];
  int t = threadIdx.x, lane = t & 63, wid = t >> 6;
  int v = (t < nb) ? bsum[t] : 0;
  int s = v;
#pragma unroll
  for (int d = 1; d < 64; d <<= 1) { int tt = __shfl_up(s, d); if (lane >= d) s += tt; }
  if (lane == 63) wsum[wid] = s;
  __syncthreads();
  if (wid == 0) {
    int w = (lane < 16) ? wsum[lane] : 0;
#pragma unroll
    for (int d = 1; d < 16; d <<= 1) { int tt = __shfl_up(w, d); if (lane >= d) w += tt; }
    if (lane < 16) wsum[lane] = w;
  }
  __syncthreads();
  int excl = s - v + ((wid > 0) ? wsum[wid - 1] : 0);
  if (t < nb) bsum[t] = excl;
}

// ---------- scan phase C: per-replica bases rb[0..NR-1] + degt ----------
__global__ __launch_bounds__(256) void kscanC(const int* __restrict__ deg8,
                                              const int* __restrict__ bsum,
                                              int* __restrict__ rb,
                                              int* __restrict__ degt, int n)
{
  __shared__ int ws[4];
  int t = threadIdx.x, lane = t & 63, wid = t >> 6;
  int i = (int)blockIdx.x * 1024 + t * 4;
  int cr[NR][4];
#pragma unroll
  for (int r = 0; r < NR; ++r) {
    if (i + 3 < n) {
      int4 v = *(const int4*)(deg8 + (size_t)r * n + i);
      cr[r][0] = v.x; cr[r][1] = v.y; cr[r][2] = v.z; cr[r][3] = v.w;
    } else {
      for (int k = 0; k < 4; ++k)
        cr[r][k] = (i + k < n) ? deg8[(size_t)r * n + i + k] : 0;
    }
  }
  int tot[4];
#pragma unroll
  for (int k = 0; k < 4; ++k) {
    int s = 0;
#pragma unroll
    for (int r = 0; r < NR; ++r) s += cr[r][k];
    tot[k] = s;
  }
  int tsum = tot[0] + tot[1] + tot[2] + tot[3];
  int s = tsum;
#pragma unroll
  for (int d = 1; d < 64; d <<= 1) { int tt = __shfl_up(s, d); if (lane >= d) s += tt; }
  if (lane == 63) ws[wid] = s;
  __syncthreads();
  if (t == 0) {
    int a = ws[0]; ws[0] = 0;
    int b = ws[1]; ws[1] = a; a += b;
    int c = ws[2]; ws[2] = a; a += c;
    ws[3] = a;
  }
  __syncthreads();
  int base = bsum[blockIdx.x] + ws[wid] + (s - tsum);
#pragma unroll
  for (int k = 0; k < 4; ++k) {
    if (i + k < n) {
      int b0 = base;
#pragma unroll
      for (int r = 0; r < NR; ++r) {
        rb[(size_t)r * n + i + k] = b0;
        b0 += cr[r][k];
      }
      degt[i + k] = tot[k];
    }
    base += tot[k];
  }
}

// ---------- CSR scatter: rank-based, ATOMIC-FREE, dst-quadrant L2-local writes ----------
__global__ __launch_bounds__(256) void kscatter(
    const int* __restrict__ ei, const unsigned* __restrict__ dstr, int e,
    const int* __restrict__ rb, int* __restrict__ csr, int n)
{
  int oct = (int)blockIdx.x & 3;
  int nsub = (int)gridDim.x >> 2;
  int sub = (int)blockIdx.x >> 2;
  int nper = (n + 3) >> 2;
  int lo = oct * nper, hi = lo + nper;
  int stride = nsub << 10;
  for (int i = (sub * 256 + (int)threadIdx.x) * 4; i < e; i += stride) {
    if (i + 3 < e) {
      uint4 d4 = *(const uint4*)(dstr + i);
      int4 s4 = *(const int4*)(ei + i);
      int dx = d4.x & 0x1ffff, dy = d4.y & 0x1ffff,
          dz = d4.z & 0x1ffff, dw = d4.w & 0x1ffff;
      if (dx >= lo && dx < hi)
        csr[rb[(size_t)((d4.x >> 17) & 7) * n + dx] + (d4.x >> 20)] = s4.x;
      if (dy >= lo && dy < hi)
        csr[rb[(size_t)((d4.y >> 17) & 7) * n + dy] + (d4.y >> 20)] = s4.y;
      if (dz >= lo && dz < hi)
        csr[rb[(size_t)((d4.z >> 17) & 7) * n + dz] + (d4.z >> 20)] = s4.z;
      if (dw >= lo && dw < hi)
        csr[rb[(size_t)((d4.w >> 17) & 7) * n + dw] + (d4.w >> 20)] = s4.w;
    } else {
      for (int k = 0; k < 4 && i + k < e; ++k) {
        unsigned dv = dstr[i + k];
        int d = dv & 0x1ffff;
        if (d >= lo && d < hi)
          csr[rb[(size_t)((dv >> 17) & 7) * n + d] + (dv >> 20)] = ei[i + k];
      }
    }
  }
}

// ---------- KAGG: raw-x aggregation + pipelined A-phase gathers ----------
__global__ __launch_bounds__(256) void kagg(
    const int* __restrict__ csr, const int* __restrict__ offs,
    const int* __restrict__ degt,
    const unsigned* __restrict__ combo, const float* __restrict__ a_d,
    unsigned* __restrict__ agg32, int n)
{
  int lane = threadIdx.x & 63;
  int wid  = threadIdx.x >> 6;
  int base = ((int)blockIdx.x * 4 + wid) * 4;      // 4 nodes per wave
  int eg = lane >> 3, ha = lane & 7;
  int hb = eg;
  int c4 = lane & 7;

  for (int t = 0; t < 4; ++t) {
    int node = base + t;
    if (node >= n) return;
    int start = offs[node];
    int dg = degt[node];
    unsigned aw_self = combo[(size_t)node * 16 + ha];
    float ad_a  = a_d[(size_t)node * HH + ha];
    float aself = leaky(bflo(aw_self) + ad_a);

    float acc0 = 0.f, acc1 = 0.f, acc2 = 0.f, acc3 = 0.f;
    float dnA = 0.f, osA = 0.f;

    // prologue: gather chunk 0
    bool vn = eg < dg;
    int srcl_n = vn ? csr[start + eg] : 0;
    unsigned av_n = vn ? combo[(size_t)srcl_n * 16 + ha] : 0u;

    for (int j0 = 0; j0 < dg; j0 += 8) {
      int cnt = dg - j0; if (cnt > 8) cnt = 8;
      bool valid = vn;
      int srcl = srcl_n;
      unsigned av = av_n;
      // prefetch next chunk (overlaps this chunk's B-phase)
      int idx2 = j0 + 8 + eg;
      vn = idx2 < dg;
      srcl_n = vn ? csr[start + idx2] : 0;
      av_n = vn ? combo[(size_t)srcl_n * 16 + ha] : 0u;

      float pw = 0.f;
      if (valid) {
        float al = leaky(bflo(av) + ad_a);
        float p  = __expf(al - aself);
        pw = p * h2f(av >> 16);                    // p * xscale_src
        dnA += p; osA += pw;
      }
      if (cnt == 8) {
#pragma unroll
        for (int j = 0; j < 8; ++j) {
          int sl = (j << 3) + hb;
          float wt = __shfl(pw, sl);
          int s = __shfl(srcl, sl);
          unsigned w = combo[(size_t)s * 16 + 8 + c4]; // second half — L2-hot
          acc0 = fmaf(ub0(w), wt, acc0);
          acc1 = fmaf(ub1(w), wt, acc1);
          acc2 = fmaf(ub2(w), wt, acc2);
          acc3 = fmaf(ub3(w), wt, acc3);
        }
      } else {
        for (int j = 0; j < cnt; ++j) {
          int sl = (j << 3) + hb;
          float wt = __shfl(pw, sl);
          int s = __shfl(srcl, sl);
          unsigned w = combo[(size_t)s * 16 + 8 + c4];
          acc0 = fmaf(ub0(w), wt, acc0);
          acc1 = fmaf(ub1(w), wt, acc1);
          acc2 = fmaf(ub2(w), wt, acc2);
          acc3 = fmaf(ub3(w), wt, acc3);
        }
      }
    }

    // reduce dn/osum over edge-slot dim (eg): after this, value is per-head ha
    float dnH = dnA, osH = osA;
    dnH += __shfl_xor(dnH, 8);  osH += __shfl_xor(osH, 8);
    dnH += __shfl_xor(dnH, 16); osH += __shfl_xor(osH, 16);
    dnH += __shfl_xor(dnH, 32); osH += __shfl_xor(osH, 32);
    float dnB = __shfl(dnH, hb);
    float osB = __shfl(osH, hb);
    float scB = __shfl(h2f(aw_self >> 16), hb);    // xscale_node (replicated)

    // self loop: p = 1
    {
      unsigned w = combo[(size_t)node * 16 + 8 + c4];
      dnB += 1.f; osB += scB;
      acc0 = fmaf(ub0(w), scB, acc0);
      acc1 = fmaf(ub1(w), scB, acc1);
      acc2 = fmaf(ub2(w), scB, acc2);
      acc3 = fmaf(ub3(w), scB, acc3);
    }

    float corr = -128.f * osB;
    float inv = 0.125f / dnB;                      // fold 1/8 head-mean here
    acc0 = (acc0 + corr) * inv;
    acc1 = (acc1 + corr) * inv;
    acc2 = (acc2 + corr) * inv;
    acc3 = (acc3 + corr) * inv;
    uint2 pk;
    pk.x = bf16r(acc0) | (bf16r(acc1) << 16);
    pk.y = bf16r(acc2) | (bf16r(acc3) << 16);
    *(uint2*)(agg32 + (size_t)node * 128 + hb * 16 + c4 * 2) = pk;
  }
}

// ---------- K5M: MFMA tail — og = agg@Wstack, + x + bg, LN1 + FFN(mfma) + LN2 ----------
__global__ __launch_bounds__(256) void k5m(
    const u16* __restrict__ agg16, const float* __restrict__ x,
    const float* __restrict__ bg, const u16* __restrict__ WSb,
    const u16* __restrict__ V1b, const u16* __restrict__ V2b,
    const float* __restrict__ b1, const float* __restrict__ b2,
    const float* __restrict__ g1, const float* __restrict__ be1,
    const float* __restrict__ g2, const float* __restrict__ be2,
    float* __restrict__ out, int n)
{
  __shared__ u16   lh[4][16 * 40];
  __shared__ u16   lf[4][16 * 136];
  __shared__ float lo[4][16 * 36];
  int wid = threadIdx.x >> 6, lane = threadIdx.x & 63;
  int q = lane & 15, g = lane >> 4;
  long node0 = (long)((int)blockIdx.x * 4 + wid) * 16;
  if (node0 + 16 > n) node0 = n - 16;
  u16* LH = lh[wid]; u16* LF = lf[wid]; float* LO = lo[wid];

  // stage x + bg cooperatively
  {
    int row = lane >> 2, off = (lane & 3) * 8;
    const float* x8 = x + (node0 + row) * CC + off;
    float4 c0 = *(const float4*)x8, c1 = *(const float4*)(x8 + 4);
    float4 bg0 = *(const float4*)(bg + off), bg1 = *(const float4*)(bg + off + 4);
    float4 s0 = make_float4(c0.x + bg0.x, c0.y + bg0.y, c0.z + bg0.z, c0.w + bg0.w);
    float4 s1 = make_float4(c1.x + bg1.x, c1.y + bg1.y, c1.z + bg1.z, c1.w + bg1.w);
    *(float4*)(LO + row * 36 + off)     = s0;
    *(float4*)(LO + row * 36 + off + 4) = s1;
  }
  __syncthreads();

  // og = agg @ Wstack  ([16,256] x [256,32]) then LO += og
  {
    f32x4 a20 = {0.f, 0.f, 0.f, 0.f}, a21 = {0.f, 0.f, 0.f, 0.f};
#pragma unroll
    for (int kb = 0; kb < 8; ++kb) {
      bf16x8 af = *(const bf16x8*)(agg16 + (node0 + q) * 256 + kb * 32 + g * 8);
      bf16x8 w0 = *(const bf16x8*)(WSb + (kb * 2 + 0) * 512 + lane * 8);
      bf16x8 w1v = *(const bf16x8*)(WSb + (kb * 2 + 1) * 512 + lane * 8);
      a20 = __builtin_amdgcn_mfma_f32_16x16x32_bf16(af, w0, a20, 0, 0, 0);
      a21 = __builtin_amdgcn_mfma_f32_16x16x32_bf16(af, w1v, a21, 0, 0, 0);
    }
#pragma unroll
    for (int r = 0; r < 4; ++r) {
      LO[(4 * g + r) * 36 + q]      += a20[r];
      LO[(4 * g + r) * 36 + 16 + q] += a21[r];
    }
  }
  __syncthreads();

  float hv[32];
  if (lane < 16) {
#pragma unroll
    for (int i = 0; i < 8; ++i) {
      float4 t = *(const float4*)(LO + q * 36 + i * 4);
      hv[4*i] = t.x; hv[4*i+1] = t.y; hv[4*i+2] = t.z; hv[4*i+3] = t.w;
    }
    float mu = 0.f;
#pragma unroll
    for (int c = 0; c < 32; ++c) mu += hv[c];
    mu *= (1.f / 32.f);
    float var = 0.f;
#pragma unroll
    for (int c = 0; c < 32; ++c) { float t = hv[c] - mu; var = fmaf(t, t, var); }
    float rs = rsqrtf(var * (1.f / 32.f) + LNEPS);
#pragma unroll
    for (int c = 0; c < 32; ++c) hv[c] = (hv[c] - mu) * rs * g1[c] + be1[c];
    uint* dst = (uint*)(LH + q * 40);
#pragma unroll
    for (int i = 0; i < 16; ++i)
      dst[i] = bf16r(hv[2*i]) | (bf16r(hv[2*i+1]) << 16);
  }
  __syncthreads();

  bf16x8 ah = *(const bf16x8*)(LH + q * 40 + g * 8);
#pragma unroll
  for (int nb = 0; nb < 8; ++nb) {
    bf16x8 v1 = *(const bf16x8*)(V1b + nb * 512 + lane * 8);
    f32x4 acc = {0.f, 0.f, 0.f, 0.f};
    acc = __builtin_amdgcn_mfma_f32_16x16x32_bf16(ah, v1, acc, 0, 0, 0);
    int col = 16 * nb + q;
    float bias = b1[col];
#pragma unroll
    for (int r = 0; r < 4; ++r) {
      float f = fmaxf(acc[r] + bias, 0.f);
      LF[(4 * g + r) * 136 + col] = (u16)bf16r(f);
    }
  }
  __syncthreads();

  f32x4 a20 = {0.f, 0.f, 0.f, 0.f}, a21 = {0.f, 0.f, 0.f, 0.f};
#pragma unroll
  for (int kb = 0; kb < 4; ++kb) {
    bf16x8 af2 = *(const bf16x8*)(LF + q * 136 + kb * 32 + g * 8);
    bf16x8 v20 = *(const bf16x8*)(V2b + (kb * 2 + 0) * 512 + lane * 8);
    bf16x8 v21 = *(const bf16x8*)(V2b + (kb * 2 + 1) * 512 + lane * 8);
    a20 = __builtin_amdgcn_mfma_f32_16x16x32_bf16(af2, v20, a20, 0, 0, 0);
    a21 = __builtin_amdgcn_mfma_f32_16x16x32_bf16(af2, v21, a21, 0, 0, 0);
  }
  __syncthreads();
#pragma unroll
  for (int r = 0; r < 4; ++r) {
    LO[(4 * g + r) * 36 + q]      = a20[r];
    LO[(4 * g + r) * 36 + 16 + q] = a21[r];
  }
  __syncthreads();

  if (lane < 16) {
    float ov[32];
#pragma unroll
    for (int i = 0; i < 8; ++i) {
      float4 t = *(const float4*)(LO + q * 36 + i * 4);
      ov[4*i] = t.x; ov[4*i+1] = t.y; ov[4*i+2] = t.z; ov[4*i+3] = t.w;
    }
#pragma unroll
    for (int c = 0; c < 32; ++c) ov[c] += b2[c] + hv[c];
    float mu2 = 0.f;
#pragma unroll
    for (int c = 0; c < 32; ++c) mu2 += ov[c];
    mu2 *= (1.f / 32.f);
    float var2 = 0.f;
#pragma unroll
    for (int c = 0; c < 32; ++c) { float t = ov[c] - mu2; var2 = fmaf(t, t, var2); }
    float rs2 = rsqrtf(var2 * (1.f / 32.f) + LNEPS);
    float* op = out + (node0 + q) * CC;
#pragma unroll
    for (int i = 0; i < 8; ++i) {
      float4 o;
      o.x = (ov[4*i]   - mu2) * rs2 * g2[4*i]   + be2[4*i];
      o.y = (ov[4*i+1] - mu2) * rs2 * g2[4*i+1] + be2[4*i+1];
      o.z = (ov[4*i+2] - mu2) * rs2 * g2[4*i+2] + be2[4*i+2];
      o.w = (ov[4*i+3] - mu2) * rs2 * g2[4*i+3] + be2[4*i+3];
      *(float4*)(op + i * 4) = o;
    }
  }
}

// ---------- launch ----------
extern "C" void kernel_launch(void* const* d_in, const int* in_sizes, int n_in,
                              void* d_out, int out_size, void* d_ws, size_t ws_size,
                              hipStream_t stream)
{
  const float* x    = (const float*)d_in[0];
  const int*   ei   = (const int*)d_in[1];
  const float* W    = (const float*)d_in[2];
  const float* atts = (const float*)d_in[3];
  const float* attd = (const float*)d_in[4];
  const float* bg   = (const float*)d_in[5];
  const float* w1   = (const float*)d_in[6];
  const float* b1   = (const float*)d_in[7];
  const float* w2   = (const float*)d_in[8];
  const float* b2   = (const float*)d_in[9];
  const float* g1   = (const float*)d_in[10];
  const float* be1  = (const float*)d_in[11];
  const float* g2   = (const float*)d_in[12];
  const float* be2  = (const float*)d_in[13];

  int n = in_sizes[0] / CC;
  int e = in_sizes[1] / 2;

  uint8_t* ws = (uint8_t*)d_ws;
  size_t o = 0;
  unsigned* combo = (unsigned*)(ws + o); o += (size_t)n * 64;    // 64B/node: ascp+xqx
  float* a_d = (float*)(ws + o); o += (size_t)n * HH * 4;
  unsigned* agg32 = (unsigned*)(ws + o); o += (size_t)n * 512;   // bf16 agg [N,256]
  int* deg8   = (int*)(ws + o); o += (size_t)n * NR * 4;
  int* rb     = (int*)(ws + o); o += (size_t)n * NR * 4;
  int* degt   = (int*)(ws + o); o += (size_t)n * 4;
  unsigned* dstr = (unsigned*)(ws + o); o += (size_t)e * 4;
  int* csr    = (int*)(ws + o); o += (size_t)e * 4;
  int* bsum   = (int*)(ws + o); o += 4096;
  u16* Zb2 = (u16*)(ws + o); o += 512 * 2;
  u16* V1b = (u16*)(ws + o); o += 8 * 512 * 2;
  u16* V2b = (u16*)(ws + o); o += 8 * 512 * 2;
  u16* WSb = (u16*)(ws + o); o += 16 * 512 * 2;

  (void)hipMemsetAsync(deg8, 0, (size_t)n * NR * 4, stream);

  int nwaves = (n + 15) / 16;
  int nbc   = (nwaves + 3) / 4;
  int nb_e4 = (e + 1023) / 1024;
  int nb_s  = (n + 1023) / 1024;
  int nb_ag = (n + 15) / 16;        // 4 waves x 4 nodes = 16 nodes per block

  klayout <<<16, 256, 0, stream>>>(W, atts, attd, w1, w2, Zb2, V1b, V2b, WSb);
  k1c     <<<nbc + nb_e4, 256, 0, stream>>>(x, Zb2, ei, combo, a_d, deg8,
                                            dstr, n, e, nbc);
  kscanA  <<<nb_s, 256, 0, stream>>>(deg8, bsum, n);
  kscanB  <<<1, 1024, 0, stream>>>(bsum, nb_s);
  kscanC  <<<nb_s, 256, 0, stream>>>(deg8, bsum, rb, degt, n);
  kscatter<<<512, 256, 0, stream>>>(ei, dstr, e, rb, csr, n);
  kagg    <<<nb_ag, 256, 0, stream>>>(csr, rb, degt, combo, a_d, agg32, n);
  k5m     <<<nbc, 256, 0, stream>>>((const u16*)agg32, x, bg, WSb, V1b, V2b,
                                    b1, b2, g1, be1, g2, be2, (float*)d_out, n);
}